// Round 14
// baseline (420.279 us; speedup 1.0000x reference)
//
#include <hip/hip_runtime.h>

#define N_NODES 50000
#define N_EDGES 800000
#define H 64
#define NB 250          // coarse buckets (node / 200)
#define NPB 200         // nodes per bucket
#define EPB 3200        // edges per pass-A/C block (250 * 3200 = 800000)
#define ASTR 65         // accumulator node stride (bank stagger)
#define NPWD 13         // nodes per wave in pass D MLP (16*13 >= 200)

typedef float floatx4 __attribute__((ext_vector_type(4)));

__device__ __forceinline__ float readlane_f(float x, int i) {
    return __int_as_float(__builtin_amdgcn_readlane(__float_as_int(x), i));
}
__device__ __forceinline__ unsigned bf16rne(float x) {
    unsigned u = __float_as_uint(x);
    return (u + 0x7FFFu + ((u >> 16) & 1u)) >> 16;
}
__device__ __forceinline__ float bf16lo(unsigned u) { return __uint_as_float(u << 16); }
__device__ __forceinline__ float bf16hi(unsigned u) { return __uint_as_float(u & 0xFFFF0000u); }

// ---- Pass A: per-block bucket histogram (LDS atomics only) ----
__global__ __launch_bounds__(256) void histA_kernel(
    const int* __restrict__ recv, unsigned* __restrict__ histMatT)
{
    __shared__ unsigned h[NB];
    const int g = blockIdx.x;
    if (threadIdx.x < NB) h[threadIdx.x] = 0;
    __syncthreads();
    for (int i = threadIdx.x; i < EPB; i += 256)
        atomicAdd(&h[recv[g * EPB + i] / NPB], 1u);
    __syncthreads();
    if (threadIdx.x < NB) histMatT[threadIdx.x * NB + g] = h[threadIdx.x];
}

// ---- Pass B1: per-bucket exclusive scan over blocks ----
__global__ __launch_bounds__(256) void scanB1_kernel(
    const unsigned* __restrict__ histMatT, unsigned* __restrict__ offMatT,
    unsigned* __restrict__ bucketTotal)
{
    __shared__ unsigned sh[256];
    const int b = blockIdx.x;
    const int t = threadIdx.x;
    unsigned vals = (t < NB) ? histMatT[b * NB + t] : 0u;
    sh[t] = vals;
    __syncthreads();
    for (int off = 1; off < 256; off <<= 1) {
        unsigned vv = (t >= off) ? sh[t - off] : 0u;
        __syncthreads();
        sh[t] += vv;
        __syncthreads();
    }
    if (t < NB) offMatT[b * NB + t] = sh[t] - vals;   // exclusive prefix over blocks
    if (t == 255) bucketTotal[b] = sh[255];
}

// ---- Pass B2: exclusive scan of bucket totals ----
__global__ __launch_bounds__(256) void scanB2_kernel(
    const unsigned* __restrict__ bucketTotal, unsigned* __restrict__ bucketStart)
{
    __shared__ unsigned sh[256];
    const int t = threadIdx.x;
    unsigned vals = (t < NB) ? bucketTotal[t] : 0u;
    sh[t] = vals;
    __syncthreads();
    for (int off = 1; off < 256; off <<= 1) {
        unsigned vv = (t >= off) ? sh[t - off] : 0u;
        __syncthreads();
        sh[t] += vv;
        __syncthreads();
    }
    if (t < NB) bucketStart[t] = sh[t] - vals;
    if (t == 255) bucketStart[NB] = sh[255];
}

// ---- Pass C: contention-free scatter. LDS cursors from offset matrix;
// each block's same-bucket rows land contiguously (~1.6KB runs). ----
__global__ __launch_bounds__(1024) void scatterC_kernel(
    const float* __restrict__ E, const int* __restrict__ recv,
    const unsigned* __restrict__ offMatT, const unsigned* __restrict__ bucketStart,
    unsigned short* __restrict__ tags, unsigned* __restrict__ Es)
{
    __shared__ unsigned cur[NB];
    __shared__ unsigned posBuf[EPB];
    const int g = blockIdx.x;
    const int t = threadIdx.x;
    if (t < NB) cur[t] = bucketStart[t] + offMatT[t * NB + g];
    __syncthreads();

    // phase 1: claim positions + write node tags
    for (int i = t; i < EPB; i += 1024) {
        int r = recv[(size_t)g * EPB + i];
        int b = r / NPB;
        unsigned pos = atomicAdd(&cur[b], 1u);   // LDS atomic
        posBuf[i] = pos;
        tags[pos] = (unsigned short)(r % NPB);
    }
    __syncthreads();

    // phase 2: sequential E read, f32->bf16, write 16B chunk of 128B row
    const floatx4* E4 = reinterpret_cast<const floatx4*>(E);
    uint4* Es4 = reinterpret_cast<uint4*>(Es);
    #pragma unroll 5
    for (int it = 0; it < (EPB * 8) / 1024; ++it) {   // 25 iters
        int slot = it * 1024 + t;
        int row = slot >> 3;
        int c = slot & 7;
        unsigned pos = posBuf[row];
        size_t edge = (size_t)g * EPB + row;
        floatx4 a = __builtin_nontemporal_load(E4 + edge * 16 + c * 2);
        floatx4 d = __builtin_nontemporal_load(E4 + edge * 16 + c * 2 + 1);
        uint4 o;
        o.x = bf16rne(a.x) | (bf16rne(a.y) << 16);
        o.y = bf16rne(a.z) | (bf16rne(a.w) << 16);
        o.z = bf16rne(d.x) | (bf16rne(d.y) << 16);
        o.w = bf16rne(d.z) | (bf16rne(d.w) << 16);
        Es4[(size_t)pos * 8 + c] = o;
    }
}

// ---- Pass D: streaming LDS scatter-add + fused MLP. One block per bucket. ----
// Phase 1: stream the bucket's rows sequentially (1KB contiguous wave-loads),
// ds_add_f32 each element into the node's LDS accumulator (stride-65 stagger).
// Phase 2: MLP reads means directly from LDS (feature-per-lane for free).
__global__ __launch_bounds__(1024, 4) void passD_kernel(
    const unsigned* __restrict__ Es, const unsigned short* __restrict__ tags,
    const unsigned* __restrict__ bucketStart, const float* __restrict__ v,
    const float* __restrict__ W0, const float* __restrict__ b0,
    const float* __restrict__ W1, const float* __restrict__ b1,
    const float* __restrict__ W2, const float* __restrict__ b2,
    float* __restrict__ out)
{
    __shared__ float sW0[128 * 64];
    __shared__ float sW1[64 * 64];
    __shared__ float sW2[64 * 64];
    __shared__ float sB[3 * 64];
    __shared__ float accL[NPB * ASTR];   // 52 KB
    __shared__ int   cntL[NPB];

    const int tid = threadIdx.x;
    const int b = blockIdx.x;

    for (int i = tid; i < 128 * 64; i += 1024) sW0[i] = W0[i];
    for (int i = tid; i < 64 * 64; i += 1024) sW1[i] = W1[i];
    for (int i = tid; i < 64 * 64; i += 1024) sW2[i] = W2[i];
    if (tid < 192) {
        sB[tid] = (tid < 64) ? b0[tid] : (tid < 128) ? b1[tid - 64] : b2[tid - 128];
    }
    for (int i = tid; i < NPB * ASTR; i += 1024) accL[i] = 0.0f;
    if (tid < NPB) cntL[tid] = 0;
    __syncthreads();

    const int gbase = (int)bucketStart[b];
    const int bcnt = (int)bucketStart[b + 1] - gbase;

    // ---- Phase 1: stream rows, scatter-add into LDS ----
    const int ck = tid & 7;               // 16B chunk within the 128B row
    const uint4* Es4 = reinterpret_cast<const uint4*>(Es);
    for (int base = 0; base < bcnt; base += 128) {
        int row = base + (tid >> 3);
        if (row < bcnt) {
            int node = tags[(size_t)gbase + row];
            uint4 q = Es4[((size_t)gbase + row) * 8 + ck];
            float* a = &accL[node * ASTR + ck * 8];
            atomicAdd(a + 0, bf16lo(q.x));
            atomicAdd(a + 1, bf16hi(q.x));
            atomicAdd(a + 2, bf16lo(q.y));
            atomicAdd(a + 3, bf16hi(q.y));
            atomicAdd(a + 4, bf16lo(q.z));
            atomicAdd(a + 5, bf16hi(q.z));
            atomicAdd(a + 6, bf16lo(q.w));
            atomicAdd(a + 7, bf16hi(q.w));
            if (ck == 0) atomicAdd(&cntL[node], 1);
        }
    }
    __syncthreads();

    // ---- Phase 2: MLP straight from LDS accumulators ----
    const int lane = tid & 63;
    const int wid = tid >> 6;

    float xa[NPWD], xv[NPWD];
    #pragma unroll
    for (int k = 0; k < NPWD; ++k) {
        int ln = wid * NPWD + k;          // wave-uniform
        xa[k] = 0.0f; xv[k] = 0.0f;
        if (ln < NPB) {
            int n = b * NPB + ln;
            float c0 = (float)cntL[ln];
            float invc = (c0 > 0.0f) ? 1.0f / c0 : 0.0f;
            xa[k] = accL[ln * ASTR + lane] * invc;
            xv[k] = v[(size_t)n * H + lane];
        }
    }

    float acc[NPWD];
    #pragma unroll
    for (int k = 0; k < NPWD; ++k) acc[k] = sB[lane];
    #pragma unroll 8
    for (int i = 0; i < 64; ++i) {
        float w = sW0[i * 64 + lane];
        #pragma unroll
        for (int k = 0; k < NPWD; ++k) acc[k] = fmaf(readlane_f(xa[k], i), w, acc[k]);
    }
    #pragma unroll 8
    for (int i = 0; i < 64; ++i) {
        float w = sW0[(64 + i) * 64 + lane];
        #pragma unroll
        for (int k = 0; k < NPWD; ++k) acc[k] = fmaf(readlane_f(xv[k], i), w, acc[k]);
    }
    float y[NPWD];
    #pragma unroll
    for (int k = 0; k < NPWD; ++k) y[k] = fmaxf(acc[k], 0.0f);

    #pragma unroll
    for (int k = 0; k < NPWD; ++k) acc[k] = sB[64 + lane];
    #pragma unroll 8
    for (int i = 0; i < 64; ++i) {
        float w = sW1[i * 64 + lane];
        #pragma unroll
        for (int k = 0; k < NPWD; ++k) acc[k] = fmaf(readlane_f(y[k], i), w, acc[k]);
    }
    float z[NPWD];
    #pragma unroll
    for (int k = 0; k < NPWD; ++k) z[k] = fmaxf(acc[k], 0.0f);

    #pragma unroll
    for (int k = 0; k < NPWD; ++k) acc[k] = sB[128 + lane];
    #pragma unroll 8
    for (int i = 0; i < 64; ++i) {
        float w = sW2[i * 64 + lane];
        #pragma unroll
        for (int k = 0; k < NPWD; ++k) acc[k] = fmaf(readlane_f(z[k], i), w, acc[k]);
    }

    #pragma unroll
    for (int k = 0; k < NPWD; ++k) {
        int ln = wid * NPWD + k;
        if (ln < NPB) {
            int n = b * NPB + ln;
            out[(size_t)n * H + lane] = acc[k];
        }
    }
}

extern "C" void kernel_launch(void* const* d_in, const int* in_sizes, int n_in,
                              void* d_out, int out_size, void* d_ws, size_t ws_size,
                              hipStream_t stream)
{
    const float* v  = (const float*)d_in[0];
    const int*   ei = (const int*)d_in[1];     // [2, 800000]; row 1 = receiver
    const float* e  = (const float*)d_in[2];
    const float* W0 = (const float*)d_in[3];
    const float* b0 = (const float*)d_in[4];
    const float* W1 = (const float*)d_in[5];
    const float* b1 = (const float*)d_in[6];
    const float* W2 = (const float*)d_in[7];
    const float* b2 = (const float*)d_in[8];
    float* out = (float*)d_out;

    // workspace layout (u32 units); every cell written before read -> no memset
    unsigned* W = (unsigned*)d_ws;
    unsigned*       histMatT    = W;                       // 62500 -> pad 62720
    unsigned*       offMatT     = W + 62720;               // 62500 -> pad 62720
    unsigned*       bucketTotal = W + 125440;              // 250 -> pad 256
    unsigned*       bucketStart = W + 125696;              // 251 -> pad 256
    unsigned short* tags        = (unsigned short*)(W + 125952);  // 800000 u16
    unsigned*       Es          = W + 525952;              // 800000 rows * 32 u32 (102.4 MB)
    const int* recv = ei + N_EDGES;

    histA_kernel<<<NB, 256, 0, stream>>>(recv, histMatT);
    scanB1_kernel<<<NB, 256, 0, stream>>>(histMatT, offMatT, bucketTotal);
    scanB2_kernel<<<1, 256, 0, stream>>>(bucketTotal, bucketStart);
    scatterC_kernel<<<NB, 1024, 0, stream>>>(e, recv, offMatT, bucketStart, tags, Es);
    passD_kernel<<<NB, 1024, 0, stream>>>(
        Es, tags, bucketStart, v, W0, b0, W1, b1, W2, b2, out);
}

// Round 15
// 125.440 us; speedup vs baseline: 3.3504x; 3.3504x over previous
//
#include <hip/hip_runtime.h>

#define N_NODES 50000
#define N_EDGES 800000
#define H 64
#define NB 250          // coarse buckets (node / 200)
#define NPB 200         // nodes per bucket
#define NPH 100         // nodes per half-bucket (pass D block)
#define EPB 3200        // edges per pass-A/C block
#define CAPD 2048       // max rows per half-bucket list
#define NPW 7           // nodes per wave in mean phase (16*7=112 >= 100)
#define XSTR 72         // Xa/Xv/Y/Z row stride (u16), 16B-aligned, bank-staggered
#define WSTR0 136       // Wt0 row stride (u16)

typedef float floatx4 __attribute__((ext_vector_type(4)));
typedef short bf16x8 __attribute__((ext_vector_type(8)));
typedef float f32x4 __attribute__((ext_vector_type(4)));

__device__ __forceinline__ unsigned bf16rne(float x) {
    unsigned u = __float_as_uint(x);
    return (u + 0x7FFFu + ((u >> 16) & 1u)) >> 16;
}
__device__ __forceinline__ float bf16lo(unsigned u) { return __uint_as_float(u << 16); }
__device__ __forceinline__ float bf16hi(unsigned u) { return __uint_as_float(u & 0xFFFF0000u); }

// ---- Pass A: per-block bucket histogram ----
__global__ __launch_bounds__(256) void histA_kernel(
    const int* __restrict__ recv, unsigned* __restrict__ histMatT)
{
    __shared__ unsigned h[NB];
    const int g = blockIdx.x;
    if (threadIdx.x < NB) h[threadIdx.x] = 0;
    __syncthreads();
    for (int i = threadIdx.x; i < EPB; i += 256)
        atomicAdd(&h[recv[g * EPB + i] / NPB], 1u);
    __syncthreads();
    if (threadIdx.x < NB) histMatT[threadIdx.x * NB + g] = h[threadIdx.x];
}

// ---- Pass B1: per-bucket exclusive scan over blocks ----
__global__ __launch_bounds__(256) void scanB1_kernel(
    const unsigned* __restrict__ histMatT, unsigned* __restrict__ offMatT,
    unsigned* __restrict__ bucketTotal)
{
    __shared__ unsigned sh[256];
    const int b = blockIdx.x;
    const int t = threadIdx.x;
    unsigned vals = (t < NB) ? histMatT[b * NB + t] : 0u;
    sh[t] = vals;
    __syncthreads();
    for (int off = 1; off < 256; off <<= 1) {
        unsigned vv = (t >= off) ? sh[t - off] : 0u;
        __syncthreads();
        sh[t] += vv;
        __syncthreads();
    }
    if (t < NB) offMatT[b * NB + t] = sh[t] - vals;
    if (t == 255) bucketTotal[b] = sh[255];
}

// ---- Pass B2: exclusive scan of bucket totals ----
__global__ __launch_bounds__(256) void scanB2_kernel(
    const unsigned* __restrict__ bucketTotal, unsigned* __restrict__ bucketStart)
{
    __shared__ unsigned sh[256];
    const int t = threadIdx.x;
    unsigned vals = (t < NB) ? bucketTotal[t] : 0u;
    sh[t] = vals;
    __syncthreads();
    for (int off = 1; off < 256; off <<= 1) {
        unsigned vv = (t >= off) ? sh[t - off] : 0u;
        __syncthreads();
        sh[t] += vv;
        __syncthreads();
    }
    if (t < NB) bucketStart[t] = sh[t] - vals;
    if (t == 255) bucketStart[NB] = sh[255];
}

// ---- Pass C: contention-free scatter (run-clustered writes) ----
__global__ __launch_bounds__(1024) void scatterC_kernel(
    const float* __restrict__ E, const int* __restrict__ recv,
    const unsigned* __restrict__ offMatT, const unsigned* __restrict__ bucketStart,
    unsigned short* __restrict__ tags, unsigned* __restrict__ Es)
{
    __shared__ unsigned cur[NB];
    __shared__ unsigned posBuf[EPB];
    const int g = blockIdx.x;
    const int t = threadIdx.x;
    if (t < NB) cur[t] = bucketStart[t] + offMatT[t * NB + g];
    __syncthreads();

    for (int i = t; i < EPB; i += 1024) {
        int r = recv[(size_t)g * EPB + i];
        int b = r / NPB;
        unsigned pos = atomicAdd(&cur[b], 1u);
        posBuf[i] = pos;
        tags[pos] = (unsigned short)(r % NPB);
    }
    __syncthreads();

    const floatx4* E4 = reinterpret_cast<const floatx4*>(E);
    uint4* Es4 = reinterpret_cast<uint4*>(Es);
    #pragma unroll 5
    for (int it = 0; it < (EPB * 8) / 1024; ++it) {
        int slot = it * 1024 + t;
        int row = slot >> 3;
        int c = slot & 7;
        unsigned pos = posBuf[row];
        size_t edge = (size_t)g * EPB + row;
        floatx4 a = __builtin_nontemporal_load(E4 + edge * 16 + c * 2);
        floatx4 d = __builtin_nontemporal_load(E4 + edge * 16 + c * 2 + 1);
        uint4 o;
        o.x = bf16rne(a.x) | (bf16rne(a.y) << 16);
        o.y = bf16rne(a.z) | (bf16rne(a.w) << 16);
        o.z = bf16rne(d.x) | (bf16rne(d.y) << 16);
        o.w = bf16rne(d.z) | (bf16rne(d.w) << 16);
        Es4[(size_t)pos * 8 + c] = o;
    }
}

// ---- Pass D: half-bucket mean (list-gather, R13-proven) + MFMA MLP ----
// Block = half-bucket (100 nodes, pad to 112 = 7 M-tiles of 16).
// Mean writes straight into MFMA A-operand layout (Xa/Xv bf16 in LDS).
// MLP: 3 layers of mfma_f32_16x16x32_bf16, W pre-transposed bf16 in LDS.
__global__ __launch_bounds__(1024, 8) void passD_kernel(
    const unsigned* __restrict__ Es, const unsigned short* __restrict__ tags,
    const unsigned* __restrict__ bucketStart, const float* __restrict__ v,
    const float* __restrict__ W0, const float* __restrict__ b0,
    const float* __restrict__ W1, const float* __restrict__ b1,
    const float* __restrict__ W2, const float* __restrict__ b2,
    float* __restrict__ out)
{
    __shared__ unsigned short Wt0[64 * WSTR0];   // Wt0[n][k]=W0[k][n], 17.4KB
    __shared__ unsigned short Wt1[64 * XSTR];    // 9.2KB
    __shared__ unsigned short Wt2[64 * XSTR];    // 9.2KB
    __shared__ unsigned short Xa[112 * XSTR];    // agg bf16; layer-1 Y reuses
    __shared__ unsigned short Xv[112 * XSTR];    // v bf16;   layer-2 Z reuses
    __shared__ float sB[3 * 64];
    __shared__ int cntL[NPH];
    __shared__ int startL[NPH];
    __shared__ int curL[NPH];
    __shared__ unsigned scanBuf[256];
    __shared__ unsigned short list[CAPD];

    const int tid = threadIdx.x;
    const int b = blockIdx.x >> 1;
    const int half = blockIdx.x & 1;

    // stage transposed bf16 weights + biases
    for (int i = tid; i < 64 * 128; i += 1024) {
        int n = i >> 7, k = i & 127;
        Wt0[n * WSTR0 + k] = (unsigned short)bf16rne(W0[k * 64 + n]);
    }
    for (int i = tid; i < 64 * 64; i += 1024) {
        int n = i >> 6, k = i & 63;
        Wt1[n * XSTR + k] = (unsigned short)bf16rne(W1[k * 64 + n]);
        Wt2[n * XSTR + k] = (unsigned short)bf16rne(W2[k * 64 + n]);
    }
    if (tid < 192)
        sB[tid] = (tid < 64) ? b0[tid] : (tid < 128) ? b1[tid - 64] : b2[tid - 128];
    for (int i = tid; i < 112 * XSTR; i += 1024) { Xa[i] = 0; Xv[i] = 0; }
    if (tid < NPH) cntL[tid] = 0;
    __syncthreads();

    const int gbase = (int)bucketStart[b];
    const int bcnt = (int)bucketStart[b + 1] - gbase;

    // per-node histogram (this half only)
    for (int i = tid; i < bcnt; i += 1024) {
        int tg = tags[(size_t)gbase + i];
        if (tg / NPH == half) atomicAdd(&cntL[tg % NPH], 1);
    }
    __syncthreads();

    // exclusive scan over 100 counters (uniform barriers)
    unsigned vals = 0;
    if (tid < 256) { vals = (tid < NPH) ? (unsigned)cntL[tid] : 0u; scanBuf[tid] = vals; }
    __syncthreads();
    for (int off = 1; off < 256; off <<= 1) {
        unsigned vv = 0;
        if (tid < 256 && tid >= off) vv = scanBuf[tid - off];
        __syncthreads();
        if (tid < 256) scanBuf[tid] += vv;
        __syncthreads();
    }
    if (tid < NPH) { startL[tid] = (int)(scanBuf[tid] - vals); curL[tid] = (int)(scanBuf[tid] - vals); }
    __syncthreads();

    // fill per-node row lists
    for (int i = tid; i < bcnt; i += 1024) {
        int tg = tags[(size_t)gbase + i];
        if (tg / NPH == half) {
            int p = atomicAdd(&curL[tg % NPH], 1);
            if (p < CAPD) list[p] = (unsigned short)i;
        }
    }
    __syncthreads();

    const int lane = tid & 63;
    const int wid = tid >> 6;
    const int rg = lane >> 3;     // row-group 0..7
    const int ck = lane & 7;      // 16B chunk 0..7
    const uint4* Es4 = reinterpret_cast<const uint4*>(Es);

    // ---- mean phase: gather rows, reduce over row-groups, write bf16 to Xa ----
    #pragma unroll
    for (int k = 0; k < NPW; ++k) {
        int ln = wid * NPW + k;
        if (ln < NPH) {
            int s0 = startL[ln];
            int c0 = cntL[ln];
            float f0 = 0.f, f1 = 0.f, f2 = 0.f, f3 = 0.f;
            float f4 = 0.f, f5 = 0.f, f6 = 0.f, f7 = 0.f;
            for (int p = 0; p < c0; p += 8) {
                int rr = p + rg;
                if (rr < c0) {
                    int idx = list[s0 + rr];
                    uint4 q = Es4[((size_t)gbase + idx) * 8 + ck];
                    f0 += bf16lo(q.x); f1 += bf16hi(q.x);
                    f2 += bf16lo(q.y); f3 += bf16hi(q.y);
                    f4 += bf16lo(q.z); f5 += bf16hi(q.z);
                    f6 += bf16lo(q.w); f7 += bf16hi(q.w);
                }
            }
            f0 += __shfl_xor(f0, 8);  f1 += __shfl_xor(f1, 8);
            f2 += __shfl_xor(f2, 8);  f3 += __shfl_xor(f3, 8);
            f4 += __shfl_xor(f4, 8);  f5 += __shfl_xor(f5, 8);
            f6 += __shfl_xor(f6, 8);  f7 += __shfl_xor(f7, 8);
            f0 += __shfl_xor(f0, 16); f1 += __shfl_xor(f1, 16);
            f2 += __shfl_xor(f2, 16); f3 += __shfl_xor(f3, 16);
            f4 += __shfl_xor(f4, 16); f5 += __shfl_xor(f5, 16);
            f6 += __shfl_xor(f6, 16); f7 += __shfl_xor(f7, 16);
            f0 += __shfl_xor(f0, 32); f1 += __shfl_xor(f1, 32);
            f2 += __shfl_xor(f2, 32); f3 += __shfl_xor(f3, 32);
            f4 += __shfl_xor(f4, 32); f5 += __shfl_xor(f5, 32);
            f6 += __shfl_xor(f6, 32); f7 += __shfl_xor(f7, 32);

            if (rg == 0) {   // lanes 0..7: chunk ck holds full sums of feats ck*8..+8
                float invc = (c0 > 0) ? 1.0f / (float)c0 : 0.0f;
                uint4 o;
                o.x = bf16rne(f0 * invc) | (bf16rne(f1 * invc) << 16);
                o.y = bf16rne(f2 * invc) | (bf16rne(f3 * invc) << 16);
                o.z = bf16rne(f4 * invc) | (bf16rne(f5 * invc) << 16);
                o.w = bf16rne(f6 * invc) | (bf16rne(f7 * invc) << 16);
                *reinterpret_cast<uint4*>(&Xa[ln * XSTR + ck * 8]) = o;
            }
        }
    }

    // ---- v rows -> Xv bf16 ----
    for (int i = tid; i < NPH * 8; i += 1024) {
        int ln = i >> 3, c = i & 7;
        int n = b * NPB + half * NPH + ln;
        const floatx4* vp = reinterpret_cast<const floatx4*>(&v[(size_t)n * H + c * 8]);
        floatx4 p = vp[0], q = vp[1];
        uint4 o;
        o.x = bf16rne(p.x) | (bf16rne(p.y) << 16);
        o.y = bf16rne(p.z) | (bf16rne(p.w) << 16);
        o.z = bf16rne(q.x) | (bf16rne(q.y) << 16);
        o.w = bf16rne(q.z) | (bf16rne(q.w) << 16);
        *reinterpret_cast<uint4*>(&Xv[ln * XSTR + c * 8]) = o;
    }
    __syncthreads();

    // ---- MFMA MLP. Units: (m-tile 0..6) x (n-tile 0..3) = 28; wave does u=wid, wid+16.
    // A: lane holds A[l&15][(l>>4)*8+j]; B: B[(l>>4)*8+j][l&15]; D: D[(l>>4)*4+r][l&15].
    const int m15 = lane & 15;
    const int khi = lane >> 4;
    const int u0 = wid, u1 = wid + 16;
    const int m0a = u0 >> 2, n0a = u0 & 3;
    const int m0b = u1 >> 2, n0b = u1 & 3;
    const bool va = (u0 < 28), vb = (u1 < 28);

    f32x4 acc0 = {0.f, 0.f, 0.f, 0.f}, acc1 = {0.f, 0.f, 0.f, 0.f};
    // layer 0: K=128 (kt 0,1 from Xa; kt 2,3 from Xv)
    if (va) {
        #pragma unroll
        for (int kt = 0; kt < 4; ++kt) {
            const unsigned short* Xs = (kt < 2) ? Xa : Xv;
            int kk = (kt & 1) * 32;
            bf16x8 a = *reinterpret_cast<const bf16x8*>(&Xs[(m0a * 16 + m15) * XSTR + kk + khi * 8]);
            bf16x8 w = *reinterpret_cast<const bf16x8*>(&Wt0[(n0a * 16 + m15) * WSTR0 + kt * 32 + khi * 8]);
            acc0 = __builtin_amdgcn_mfma_f32_16x16x32_bf16(a, w, acc0, 0, 0, 0);
        }
    }
    if (vb) {
        #pragma unroll
        for (int kt = 0; kt < 4; ++kt) {
            const unsigned short* Xs = (kt < 2) ? Xa : Xv;
            int kk = (kt & 1) * 32;
            bf16x8 a = *reinterpret_cast<const bf16x8*>(&Xs[(m0b * 16 + m15) * XSTR + kk + khi * 8]);
            bf16x8 w = *reinterpret_cast<const bf16x8*>(&Wt0[(n0b * 16 + m15) * WSTR0 + kt * 32 + khi * 8]);
            acc1 = __builtin_amdgcn_mfma_f32_16x16x32_bf16(a, w, acc1, 0, 0, 0);
        }
    }
    __syncthreads();   // all Xa/Xv reads done
    // Y = relu(acc + b0) -> Xa region (bf16 per-element stores)
    if (va) {
        float bb = sB[n0a * 16 + m15];
        #pragma unroll
        for (int r = 0; r < 4; ++r) {
            int node = m0a * 16 + khi * 4 + r;
            Xa[node * XSTR + n0a * 16 + m15] = (unsigned short)bf16rne(fmaxf(acc0[r] + bb, 0.0f));
        }
    }
    if (vb) {
        float bb = sB[n0b * 16 + m15];
        #pragma unroll
        for (int r = 0; r < 4; ++r) {
            int node = m0b * 16 + khi * 4 + r;
            Xa[node * XSTR + n0b * 16 + m15] = (unsigned short)bf16rne(fmaxf(acc1[r] + bb, 0.0f));
        }
    }
    __syncthreads();

    // layer 1: K=64 from Xa(Y)
    acc0 = (f32x4){0.f, 0.f, 0.f, 0.f}; acc1 = (f32x4){0.f, 0.f, 0.f, 0.f};
    if (va) {
        #pragma unroll
        for (int kt = 0; kt < 2; ++kt) {
            bf16x8 a = *reinterpret_cast<const bf16x8*>(&Xa[(m0a * 16 + m15) * XSTR + kt * 32 + khi * 8]);
            bf16x8 w = *reinterpret_cast<const bf16x8*>(&Wt1[(n0a * 16 + m15) * XSTR + kt * 32 + khi * 8]);
            acc0 = __builtin_amdgcn_mfma_f32_16x16x32_bf16(a, w, acc0, 0, 0, 0);
        }
    }
    if (vb) {
        #pragma unroll
        for (int kt = 0; kt < 2; ++kt) {
            bf16x8 a = *reinterpret_cast<const bf16x8*>(&Xa[(m0b * 16 + m15) * XSTR + kt * 32 + khi * 8]);
            bf16x8 w = *reinterpret_cast<const bf16x8*>(&Wt1[(n0b * 16 + m15) * XSTR + kt * 32 + khi * 8]);
            acc1 = __builtin_amdgcn_mfma_f32_16x16x32_bf16(a, w, acc1, 0, 0, 0);
        }
    }
    __syncthreads();
    // Z = relu(acc + b1) -> Xv region
    if (va) {
        float bb = sB[64 + n0a * 16 + m15];
        #pragma unroll
        for (int r = 0; r < 4; ++r) {
            int node = m0a * 16 + khi * 4 + r;
            Xv[node * XSTR + n0a * 16 + m15] = (unsigned short)bf16rne(fmaxf(acc0[r] + bb, 0.0f));
        }
    }
    if (vb) {
        float bb = sB[64 + n0b * 16 + m15];
        #pragma unroll
        for (int r = 0; r < 4; ++r) {
            int node = m0b * 16 + khi * 4 + r;
            Xv[node * XSTR + n0b * 16 + m15] = (unsigned short)bf16rne(fmaxf(acc1[r] + bb, 0.0f));
        }
    }
    __syncthreads();

    // layer 2: K=64 from Xv(Z); no activation; store to global
    acc0 = (f32x4){0.f, 0.f, 0.f, 0.f}; acc1 = (f32x4){0.f, 0.f, 0.f, 0.f};
    if (va) {
        #pragma unroll
        for (int kt = 0; kt < 2; ++kt) {
            bf16x8 a = *reinterpret_cast<const bf16x8*>(&Xv[(m0a * 16 + m15) * XSTR + kt * 32 + khi * 8]);
            bf16x8 w = *reinterpret_cast<const bf16x8*>(&Wt2[(n0a * 16 + m15) * XSTR + kt * 32 + khi * 8]);
            acc0 = __builtin_amdgcn_mfma_f32_16x16x32_bf16(a, w, acc0, 0, 0, 0);
        }
        float bb = sB[128 + n0a * 16 + m15];
        #pragma unroll
        for (int r = 0; r < 4; ++r) {
            int node = m0a * 16 + khi * 4 + r;
            if (node < NPH) {
                int n = b * NPB + half * NPH + node;
                out[(size_t)n * H + n0a * 16 + m15] = acc0[r] + bb;
            }
        }
    }
    if (vb) {
        #pragma unroll
        for (int kt = 0; kt < 2; ++kt) {
            bf16x8 a = *reinterpret_cast<const bf16x8*>(&Xv[(m0b * 16 + m15) * XSTR + kt * 32 + khi * 8]);
            bf16x8 w = *reinterpret_cast<const bf16x8*>(&Wt2[(n0b * 16 + m15) * XSTR + kt * 32 + khi * 8]);
            acc1 = __builtin_amdgcn_mfma_f32_16x16x32_bf16(a, w, acc1, 0, 0, 0);
        }
        float bb = sB[128 + n0b * 16 + m15];
        #pragma unroll
        for (int r = 0; r < 4; ++r) {
            int node = m0b * 16 + khi * 4 + r;
            if (node < NPH) {
                int n = b * NPB + half * NPH + node;
                out[(size_t)n * H + n0b * 16 + m15] = acc1[r] + bb;
            }
        }
    }
}

extern "C" void kernel_launch(void* const* d_in, const int* in_sizes, int n_in,
                              void* d_out, int out_size, void* d_ws, size_t ws_size,
                              hipStream_t stream)
{
    const float* v  = (const float*)d_in[0];
    const int*   ei = (const int*)d_in[1];     // [2, 800000]; row 1 = receiver
    const float* e  = (const float*)d_in[2];
    const float* W0 = (const float*)d_in[3];
    const float* b0 = (const float*)d_in[4];
    const float* W1 = (const float*)d_in[5];
    const float* b1 = (const float*)d_in[6];
    const float* W2 = (const float*)d_in[7];
    const float* b2 = (const float*)d_in[8];
    float* out = (float*)d_out;

    // workspace layout (u32 units); every cell written before read -> no memset
    unsigned* W = (unsigned*)d_ws;
    unsigned*       histMatT    = W;                       // 62500 -> pad 62720
    unsigned*       offMatT     = W + 62720;               // 62500 -> pad 62720
    unsigned*       bucketTotal = W + 125440;              // 250 -> pad 256
    unsigned*       bucketStart = W + 125696;              // 251 -> pad 256
    unsigned short* tags        = (unsigned short*)(W + 125952);  // 800000 u16
    unsigned*       Es          = W + 525952;              // 800000 rows * 32 u32 (102.4 MB)
    const int* recv = ei + N_EDGES;

    histA_kernel<<<NB, 256, 0, stream>>>(recv, histMatT);
    scanB1_kernel<<<NB, 256, 0, stream>>>(histMatT, offMatT, bucketTotal);
    scanB2_kernel<<<1, 256, 0, stream>>>(bucketTotal, bucketStart);
    scatterC_kernel<<<NB, 1024, 0, stream>>>(e, recv, offMatT, bucketStart, tags, Es);
    passD_kernel<<<2 * NB, 1024, 0, stream>>>(
        Es, tags, bucketStart, v, W0, b0, W1, b1, W2, b2, out);
}